// Round 2
// baseline (46627.374 us; speedup 1.0000x reference)
//
#include <hip/hip_runtime.h>
#include <hip/hip_bf16.h>

#define B_SZ 1024
#define T_ENC 384
#define T_DEC 128
#define I_SZ 128
#define H_SZ 512

typedef __attribute__((ext_vector_type(8))) short short8;
typedef __attribute__((ext_vector_type(4))) float floatx4;
typedef unsigned short ushort_t;

__device__ __forceinline__ ushort_t f2bf(float x) {
    union { float f; unsigned int i; } v; v.f = x;
    unsigned int u = v.i;
    unsigned int r = (u + 0x7fffu + ((u >> 16) & 1u)) >> 16;
    return (ushort_t)r;
}
__device__ __forceinline__ float sigm(float x) { return 1.0f / (1.0f + __expf(-x)); }

// fp32 -> bf16 bulk convert (weights, once per launch). n % 1024 == 0.
__global__ __launch_bounds__(256) void cvt_f32_bf16(
    const float* __restrict__ src, ushort_t* __restrict__ dst, int n)
{
    int i = (blockIdx.x * 256 + threadIdx.x) * 4;
    if (i < n) {
        float4 v = *(const float4*)(src + i);
        short4 s = { (short)f2bf(v.x), (short)f2bf(v.y), (short)f2bf(v.z), (short)f2bf(v.w) };
        *(short4*)(dst + i) = s;
    }
}

// Fused LSTM cell step. A sources fp32 (cvt->bf16 during LDS staging),
// W pre-converted bf16, c fp32 in-place, h_out fp32.
// Tile: BM=64 rows x BN=32 h-cols (x4 gates = 128 z-cols). Wave w owns rows
// [w*16,w*16+16) and ALL 4 gates -> fully per-lane epilogue.
#define BM 64
#define BN 32
#define KC 64
#define LDSW (KC + 8)   // bf16 pad: keeps 8B alignment of short4 stores, breaks bank stride

__global__ __launch_bounds__(256) void lstm_step(
    const float* __restrict__ A1, int lda1, int K1,     // (B x K1), row stride lda1 (fp32)
    const ushort_t* __restrict__ W1,                    // (4H x K1) row-major bf16
    const float* __restrict__ A2,                       // h_in (B x H) fp32
    const ushort_t* __restrict__ W2,                    // (4H x H) bf16
    const float* __restrict__ b_ih,                     // fp32
    const float* __restrict__ b_hh,                     // fp32
    float* __restrict__ c,                              // (B x H) fp32 in-place
    float* __restrict__ h_out)                          // (B x H) fp32
{
    __shared__ short As[BM * LDSW];        // 64 x 72 bf16
    __shared__ short Ws[4 * BN * LDSW];    // 128 x 72 bf16

    const int tid  = threadIdx.x;
    const int wave = tid >> 6;
    const int lane = tid & 63;
    const int quad = lane >> 4;
    const int l15  = lane & 15;
    const int row0 = blockIdx.x * BM;
    const int col0 = blockIdx.y * BN;

    floatx4 acc[4][2];
#pragma unroll
    for (int g = 0; g < 4; ++g)
#pragma unroll
        for (int n = 0; n < 2; ++n)
            acc[g][n] = (floatx4){0.f, 0.f, 0.f, 0.f};

    const int KT = K1 + H_SZ;
    for (int kb = 0; kb < KT; kb += KC) {
        const float*    asrc; int ald;
        const ushort_t* wsrc; int wld;
        if (kb < K1) { asrc = A1 + kb;        ald = lda1; wsrc = W1 + kb;        wld = K1;  }
        else         { asrc = A2 + (kb - K1); ald = H_SZ; wsrc = W2 + (kb - K1); wld = H_SZ; }

        // stage A: 64 rows x 16 float4 chunks, cvt fp32->bf16
#pragma unroll
        for (int it = 0; it < 4; ++it) {
            int idx = tid + it * 256;            // 0..1023
            int r = idx >> 4, cc = idx & 15;
            float4 v = *(const float4*)(asrc + (size_t)(row0 + r) * ald + cc * 4);
            short4 s = { (short)f2bf(v.x), (short)f2bf(v.y), (short)f2bf(v.z), (short)f2bf(v.w) };
            *(short4*)(void*)&As[r * LDSW + cc * 4] = s;
        }
        // stage W (bf16): 4 gates x 32 rows x 8 chunks of 8 bf16 (16B)
#pragma unroll
        for (int it = 0; it < 4; ++it) {
            int idx = tid + it * 256;            // 0..1023
            int rr = idx >> 3, cch = idx & 7;    // rr = g*32 + r
            int g = rr >> 5, r = rr & 31;
            int4 v = *(const int4*)(const void*)(wsrc + (size_t)(g * H_SZ + col0 + r) * wld + cch * 8);
            *(int4*)(void*)&Ws[rr * LDSW + cch * 8] = v;
        }
        __syncthreads();

#pragma unroll
        for (int ks = 0; ks < 2; ++ks) {
            const int ko = ks * 32 + quad * 8;
            short8 a = *(const short8*)(const void*)&As[(wave * 16 + l15) * LDSW + ko];
#pragma unroll
            for (int g = 0; g < 4; ++g)
#pragma unroll
                for (int n = 0; n < 2; ++n) {
                    short8 b = *(const short8*)(const void*)&Ws[(g * BN + n * 16 + l15) * LDSW + ko];
                    acc[g][n] = __builtin_amdgcn_mfma_f32_16x16x32_bf16(a, b, acc[g][n], 0, 0, 0);
                }
        }
        __syncthreads();
    }

    // epilogue: all 4 gates for cell (row, col) live in this lane
#pragma unroll
    for (int n = 0; n < 2; ++n) {
        const int gcol = col0 + n * 16 + l15;
        const float bi = b_ih[0 * H_SZ + gcol] + b_hh[0 * H_SZ + gcol];
        const float bf = b_ih[1 * H_SZ + gcol] + b_hh[1 * H_SZ + gcol];
        const float bg = b_ih[2 * H_SZ + gcol] + b_hh[2 * H_SZ + gcol];
        const float bo = b_ih[3 * H_SZ + gcol] + b_hh[3 * H_SZ + gcol];
#pragma unroll
        for (int r = 0; r < 4; ++r) {
            const int grow = row0 + wave * 16 + quad * 4 + r;
            const size_t idx = (size_t)grow * H_SZ + gcol;
            const float zi = acc[0][n][r] + bi;
            const float zf = acc[1][n][r] + bf;
            const float zg = acc[2][n][r] + bg;
            const float zo = acc[3][n][r] + bo;
            const float cn = sigm(zf) * c[idx] + sigm(zi) * tanhf(zg);
            c[idx] = cn;
            h_out[idx] = sigm(zo) * tanhf(cn);
        }
    }
}

// FC head: nxt = h1 @ fc_w^T + fc_b  (M=1024, N=128, K=512); fp32 out + fp32 nxt
__global__ __launch_bounds__(256) void fc_step(
    const float* __restrict__ h1, const ushort_t* __restrict__ fc_w,
    const float* __restrict__ fc_b, float* __restrict__ out,
    int t, float* __restrict__ nxt)
{
    __shared__ short As[64 * LDSW];
    __shared__ short Ws[64 * LDSW];

    const int tid  = threadIdx.x;
    const int wave = tid >> 6;
    const int lane = tid & 63;
    const int quad = lane >> 4;
    const int l15  = lane & 15;
    const int row0 = blockIdx.x * 64;
    const int col0 = blockIdx.y * 64;

    floatx4 acc[4];
#pragma unroll
    for (int n = 0; n < 4; ++n) acc[n] = (floatx4){0.f, 0.f, 0.f, 0.f};

    for (int kb = 0; kb < H_SZ; kb += KC) {
        // stage A (fp32 h1 -> bf16)
#pragma unroll
        for (int it = 0; it < 4; ++it) {
            int idx = tid + it * 256;            // 0..1023
            int r = idx >> 4, cc = idx & 15;
            float4 v = *(const float4*)(h1 + (size_t)(row0 + r) * H_SZ + kb + cc * 4);
            short4 s = { (short)f2bf(v.x), (short)f2bf(v.y), (short)f2bf(v.z), (short)f2bf(v.w) };
            *(short4*)(void*)&As[r * LDSW + cc * 4] = s;
        }
        // stage W (bf16)
#pragma unroll
        for (int it = 0; it < 2; ++it) {
            int idx = tid + it * 256;            // 0..511
            int r = idx >> 3, cch = idx & 7;
            int4 v = *(const int4*)(const void*)(fc_w + (size_t)(col0 + r) * H_SZ + kb + cch * 8);
            *(int4*)(void*)&Ws[r * LDSW + cch * 8] = v;
        }
        __syncthreads();
#pragma unroll
        for (int ks = 0; ks < 2; ++ks) {
            const int ko = ks * 32 + quad * 8;
            short8 a = *(const short8*)(const void*)&As[(wave * 16 + l15) * LDSW + ko];
#pragma unroll
            for (int n = 0; n < 4; ++n) {
                short8 b = *(const short8*)(const void*)&Ws[(n * 16 + l15) * LDSW + ko];
                acc[n] = __builtin_amdgcn_mfma_f32_16x16x32_bf16(a, b, acc[n], 0, 0, 0);
            }
        }
        __syncthreads();
    }

#pragma unroll
    for (int n = 0; n < 4; ++n) {
        const int col = col0 + n * 16 + l15;
        const float bias = fc_b[col];
#pragma unroll
        for (int r = 0; r < 4; ++r) {
            const int row = row0 + wave * 16 + quad * 4 + r;
            const float v = acc[n][r] + bias;
            out[((size_t)row * T_DEC + t) * I_SZ + col] = v;
            nxt[(size_t)row * I_SZ + col] = v;
        }
    }
}

// dec_in = x[:, -1, :]  (fp32)
__global__ void copy_last(const float* __restrict__ x, float* __restrict__ nxt)
{
    int i = blockIdx.x * 256 + threadIdx.x;           // 0 .. 131071
    int b = i >> 7, k = i & 127;
    nxt[i] = x[((size_t)b * T_ENC + (T_ENC - 1)) * I_SZ + k];
}

extern "C" void kernel_launch(void* const* d_in, const int* in_sizes, int n_in,
                              void* d_out, int out_size, void* d_ws, size_t ws_size,
                              hipStream_t stream)
{
    const float* x     = (const float*)d_in[0];
    const float* W_ih0 = (const float*)d_in[1];
    const float* W_hh0 = (const float*)d_in[2];
    const float* b_ih0 = (const float*)d_in[3];
    const float* b_hh0 = (const float*)d_in[4];
    const float* W_ih1 = (const float*)d_in[5];
    const float* W_hh1 = (const float*)d_in[6];
    const float* b_ih1 = (const float*)d_in[7];
    const float* b_hh1 = (const float*)d_in[8];
    const float* fc_w  = (const float*)d_in[9];
    const float* fc_b  = (const float*)d_in[10];
    float* out = (float*)d_out;

    // workspace carve (all 16B-aligned sizes)
    const int NW_IH0 = 4 * H_SZ * I_SZ;   // 262144
    const int NW_HH  = 4 * H_SZ * H_SZ;   // 1048576
    const int NW_FC  = I_SZ * H_SZ;       // 65536
    char* w = (char*)d_ws;
    ushort_t* wb_ih0 = (ushort_t*)w;  w += (size_t)NW_IH0 * 2;
    ushort_t* wb_hh0 = (ushort_t*)w;  w += (size_t)NW_HH  * 2;
    ushort_t* wb_ih1 = (ushort_t*)w;  w += (size_t)NW_HH  * 2;
    ushort_t* wb_hh1 = (ushort_t*)w;  w += (size_t)NW_HH  * 2;
    ushort_t* wb_fc  = (ushort_t*)w;  w += (size_t)NW_FC  * 2;
    const size_t HBUF = (size_t)B_SZ * H_SZ * 4;   // 2 MB fp32
    const size_t NBUF = (size_t)B_SZ * I_SZ * 4;   // 512 KB fp32
    float* h0a = (float*)w;  w += HBUF;
    float* h0b = (float*)w;  w += HBUF;
    float* h1a = (float*)w;  w += HBUF;
    float* h1b = (float*)w;  w += HBUF;
    float* c0  = (float*)w;  w += HBUF;
    float* c1  = (float*)w;  w += HBUF;
    float* nxa = (float*)w;  w += NBUF;
    float* nxb = (float*)w;  w += NBUF;

    // weights -> bf16 (once per launch; part of the graph)
    cvt_f32_bf16<<<NW_IH0 / 1024, 256, 0, stream>>>(W_ih0, wb_ih0, NW_IH0);
    cvt_f32_bf16<<<NW_HH  / 1024, 256, 0, stream>>>(W_hh0, wb_hh0, NW_HH);
    cvt_f32_bf16<<<NW_HH  / 1024, 256, 0, stream>>>(W_ih1, wb_ih1, NW_HH);
    cvt_f32_bf16<<<NW_HH  / 1024, 256, 0, stream>>>(W_hh1, wb_hh1, NW_HH);
    cvt_f32_bf16<<<NW_FC  / 1024, 256, 0, stream>>>(fc_w,  wb_fc,  NW_FC);

    hipMemsetAsync(h0a, 0, HBUF, stream);
    hipMemsetAsync(h1a, 0, HBUF, stream);
    hipMemsetAsync(c0, 0, HBUF, stream);
    hipMemsetAsync(c1, 0, HBUF, stream);

    copy_last<<<512, 256, 0, stream>>>(x, nxa);

    const dim3 lgrid(B_SZ / BM, H_SZ / BN);   // 16 x 16
    const dim3 fgrid(B_SZ / 64, I_SZ / 64);   // 16 x 2

    float *h0c = h0a, *h0n = h0b, *h1c = h1a, *h1n = h1b;

    // encoder: both layers per timestep
    for (int t = 0; t < T_ENC; ++t) {
        lstm_step<<<lgrid, 256, 0, stream>>>(x + (size_t)t * I_SZ, T_ENC * I_SZ, I_SZ,
                                             wb_ih0, h0c, wb_hh0, b_ih0, b_hh0, c0, h0n);
        { float* tmp = h0c; h0c = h0n; h0n = tmp; }
        lstm_step<<<lgrid, 256, 0, stream>>>(h0c, H_SZ, H_SZ,
                                             wb_ih1, h1c, wb_hh1, b_ih1, b_hh1, c1, h1n);
        { float* tmp = h1c; h1c = h1n; h1n = tmp; }
    }

    // decoder
    float *ic = nxa, *inx = nxb;
    for (int t = 0; t < T_DEC; ++t) {
        lstm_step<<<lgrid, 256, 0, stream>>>(ic, I_SZ, I_SZ,
                                             wb_ih0, h0c, wb_hh0, b_ih0, b_hh0, c0, h0n);
        { float* tmp = h0c; h0c = h0n; h0n = tmp; }
        lstm_step<<<lgrid, 256, 0, stream>>>(h0c, H_SZ, H_SZ,
                                             wb_ih1, h1c, wb_hh1, b_ih1, b_hh1, c1, h1n);
        { float* tmp = h1c; h1c = h1n; h1n = tmp; }
        fc_step<<<fgrid, 256, 0, stream>>>(h1c, wb_fc, fc_b, out, t, inx);
        { float* tmp = ic; ic = inx; inx = tmp; }
    }
}

// Round 3
// 23001.021 us; speedup vs baseline: 2.0272x; 2.0272x over previous
//
#include <hip/hip_runtime.h>
#include <hip/hip_bf16.h>

#define B_SZ 1024
#define T_ENC 384
#define T_DEC 128
#define I_SZ 128
#define H_SZ 512

typedef __attribute__((ext_vector_type(8))) short short8;
typedef __attribute__((ext_vector_type(4))) float floatx4;
typedef unsigned short ushort_t;

__device__ __forceinline__ ushort_t f2bf(float x) {
    union { float f; unsigned int i; } v; v.f = x;
    unsigned int u = v.i;
    unsigned int r = (u + 0x7fffu + ((u >> 16) & 1u)) >> 16;
    return (ushort_t)r;
}
__device__ __forceinline__ float sigm(float x) { return 1.0f / (1.0f + __expf(-x)); }

// fp32 -> bf16 bulk convert (weights, once per launch). n % 1024 == 0.
__global__ __launch_bounds__(256) void cvt_f32_bf16(
    const float* __restrict__ src, ushort_t* __restrict__ dst, int n)
{
    int i = (blockIdx.x * 256 + threadIdx.x) * 4;
    if (i < n) {
        float4 v = *(const float4*)(src + i);
        short4 s = { (short)f2bf(v.x), (short)f2bf(v.y), (short)f2bf(v.z), (short)f2bf(v.w) };
        *(short4*)(dst + i) = s;
    }
}

// dec_in(t=0) = bf16(x[:, -1, :])
__global__ void copy_last(const float* __restrict__ x, ushort_t* __restrict__ dst)
{
    int i = blockIdx.x * 256 + threadIdx.x;           // 0 .. 131071
    int b = i >> 7, k = i & 127;
    dst[i] = f2bf(x[((size_t)b * T_ENC + (T_ENC - 1)) * I_SZ + k]);
}

#define BM 64
#define BN 32
#define KC 64
#define LDSW (KC + 8)    // 72 shorts: 144B row stride, 16B-aligned, breaks bank stride
#define DLW  (I_SZ + 8)  // 136 shorts: DecIn stride

// XCD-aware swizzle: bid%8 = XCD (dispatch round-robin heuristic). Pin 2 col-groups
// per XCD so each XCD's weight slice (~832 KB total both layers) stays L2-resident
// across all ~900 steps.
__device__ __forceinline__ void tile_of(int bid, int& row0, int& col0) {
    int xcd = bid & 7, q = bid >> 3;          // q in [0,32)
    int cg = xcd * 2 + (q & 1);               // col-group 0..15
    int rg = q >> 1;                          // row-group 0..15
    row0 = rg * BM; col0 = cg * BN;
}

// One LSTM cell step tile. A1 either fp32 (encoder x) or bf16; A2 = h bf16.
// Wave w owns rows [w*16,w*16+16) and ALL 4 gates -> per-lane epilogue.
template<bool A1F32>
__device__ __forceinline__ void lstm_task(
    int bid,
    const void* __restrict__ A1v, int lda1, int K1,
    const ushort_t* __restrict__ W1,                 // (4H x K1) bf16
    const ushort_t* __restrict__ A2,                 // h_in (B x H) bf16
    const ushort_t* __restrict__ W2,                 // (4H x H) bf16
    const float* __restrict__ b_ih, const float* __restrict__ b_hh,
    float* __restrict__ c, ushort_t* __restrict__ h_out,
    short* As, short* Ws)
{
    const int tid  = threadIdx.x;
    const int wave = tid >> 6;
    const int lane = tid & 63;
    const int quad = lane >> 4;
    const int l15  = lane & 15;
    int row0, col0; tile_of(bid, row0, col0);

    floatx4 acc[4][2];
#pragma unroll
    for (int g = 0; g < 4; ++g)
#pragma unroll
        for (int n = 0; n < 2; ++n)
            acc[g][n] = (floatx4){0.f, 0.f, 0.f, 0.f};

    const int KT = K1 + H_SZ;
    for (int kb = 0; kb < KT; kb += KC) {
        const ushort_t* wsrc; int wld;
        if (kb < K1) { wsrc = W1 + kb;        wld = K1;  }
        else         { wsrc = W2 + (kb - K1); wld = H_SZ; }

        // stage A (64 x 64 bf16)
        if (A1F32 && kb < K1) {
            const float* af = (const float*)A1v + kb;
#pragma unroll
            for (int it = 0; it < 4; ++it) {
                int idx = tid + it * 256;          // 0..1023
                int r = idx >> 4, cc2 = idx & 15;
                float4 v = *(const float4*)(af + (size_t)(row0 + r) * lda1 + cc2 * 4);
                short4 s = { (short)f2bf(v.x), (short)f2bf(v.y), (short)f2bf(v.z), (short)f2bf(v.w) };
                *(short4*)(void*)&As[r * LDSW + cc2 * 4] = s;
            }
        } else {
            const ushort_t* ab; int ald;
            if (kb < K1) { ab = (const ushort_t*)A1v + kb; ald = lda1; }
            else         { ab = A2 + (kb - K1);            ald = H_SZ; }
#pragma unroll
            for (int it = 0; it < 2; ++it) {
                int idx = tid + it * 256;          // 0..511
                int r = idx >> 3, cch = idx & 7;
                int4 v = *(const int4*)(const void*)(ab + (size_t)(row0 + r) * ald + cch * 8);
                *(int4*)(void*)&As[r * LDSW + cch * 8] = v;
            }
        }
        // stage W: 4 gates x 32 rows x 8 chunks (16B)
#pragma unroll
        for (int it = 0; it < 4; ++it) {
            int idx = tid + it * 256;              // 0..1023
            int rr = idx >> 3, cch = idx & 7;      // rr = g*32 + r
            int g = rr >> 5, r = rr & 31;
            int4 v = *(const int4*)(const void*)(wsrc + (size_t)(g * H_SZ + col0 + r) * wld + cch * 8);
            *(int4*)(void*)&Ws[rr * LDSW + cch * 8] = v;
        }
        __syncthreads();

#pragma unroll
        for (int ks = 0; ks < 2; ++ks) {
            const int ko = ks * 32 + quad * 8;
            short8 a = *(const short8*)(const void*)&As[(wave * 16 + l15) * LDSW + ko];
#pragma unroll
            for (int g = 0; g < 4; ++g)
#pragma unroll
                for (int n = 0; n < 2; ++n) {
                    short8 b = *(const short8*)(const void*)&Ws[(g * BN + n * 16 + l15) * LDSW + ko];
                    acc[g][n] = __builtin_amdgcn_mfma_f32_16x16x32_bf16(a, b, acc[g][n], 0, 0, 0);
                }
        }
        __syncthreads();
    }

#pragma unroll
    for (int n = 0; n < 2; ++n) {
        const int gcol = col0 + n * 16 + l15;
        const float bi = b_ih[0 * H_SZ + gcol] + b_hh[0 * H_SZ + gcol];
        const float bf = b_ih[1 * H_SZ + gcol] + b_hh[1 * H_SZ + gcol];
        const float bg = b_ih[2 * H_SZ + gcol] + b_hh[2 * H_SZ + gcol];
        const float bo = b_ih[3 * H_SZ + gcol] + b_hh[3 * H_SZ + gcol];
#pragma unroll
        for (int r = 0; r < 4; ++r) {
            const int grow = row0 + wave * 16 + quad * 4 + r;
            const size_t idx = (size_t)grow * H_SZ + gcol;
            const float zi = acc[0][n][r] + bi;
            const float zf = acc[1][n][r] + bf;
            const float zg = acc[2][n][r] + bg;
            const float zo = acc[3][n][r] + bo;
            const float cn = sigm(zf) * c[idx] + sigm(zi) * tanhf(zg);
            c[idx] = cn;
            h_out[idx] = f2bf(sigm(zo) * tanhf(cn));
        }
    }
}

// Fused encoder step: blocks 0..255 run L0(t) (if x_t), 256..511 run L1(t-1) (if h0A).
__global__ __launch_bounds__(256) void enc_pair(
    const float* __restrict__ x_t, int ldx,
    const ushort_t* __restrict__ Wih0, const ushort_t* __restrict__ h0in,
    const ushort_t* __restrict__ Whh0,
    const float* __restrict__ bih0, const float* __restrict__ bhh0,
    float* __restrict__ c0, ushort_t* __restrict__ h0out,
    const ushort_t* __restrict__ h0A,
    const ushort_t* __restrict__ Wih1, const ushort_t* __restrict__ h1in,
    const ushort_t* __restrict__ Whh1,
    const float* __restrict__ bih1, const float* __restrict__ bhh1,
    float* __restrict__ c1, ushort_t* __restrict__ h1out)
{
    __shared__ short As[BM * LDSW];
    __shared__ short Ws[4 * BN * LDSW];
    int bid = blockIdx.x;
    if (bid < 256) {
        if (x_t)
            lstm_task<true>(bid, x_t, ldx, I_SZ, Wih0, h0in, Whh0, bih0, bhh0, c0, h0out, As, Ws);
    } else {
        if (h0A)
            lstm_task<false>(bid - 256, h0A, H_SZ, H_SZ, Wih1, h1in, Whh1, bih1, bhh1, c1, h1out, As, Ws);
    }
}

// Plain single LSTM step (decoder L1), bf16 A1.
__global__ __launch_bounds__(256) void lstm_one(
    const ushort_t* __restrict__ A1, int lda1, int K1,
    const ushort_t* __restrict__ W1,
    const ushort_t* __restrict__ A2, const ushort_t* __restrict__ W2,
    const float* __restrict__ bih, const float* __restrict__ bhh,
    float* __restrict__ c, ushort_t* __restrict__ h)
{
    __shared__ short As[BM * LDSW];
    __shared__ short Ws[4 * BN * LDSW];
    lstm_task<false>(blockIdx.x, A1, lda1, K1, W1, A2, W2, bih, bhh, c, h, As, Ws);
}

// Decoder L0(t) with fused fc(t-1) prologue. fc is stateless -> each col-group
// recomputes the 64x128 dec_in tile it needs (redundant but correct); cg==0 also
// writes out[:, t-1, :] (fp32).
__global__ __launch_bounds__(256) void dec_l0(
    const ushort_t* __restrict__ h1prev,   // bf16 (B x H), null at t==0
    const ushort_t* __restrict__ fcw,      // bf16 (I x H)
    const float* __restrict__ fcb,
    float* __restrict__ outp,              // out + (t-1)*I_SZ, null at t==0
    const ushort_t* __restrict__ dec0,     // bf16 (B x I), used at t==0
    const ushort_t* __restrict__ W1,       // wb_ih0 (4H x I)
    const ushort_t* __restrict__ h0in, const ushort_t* __restrict__ W2,
    const float* __restrict__ bih, const float* __restrict__ bhh,
    float* __restrict__ c, ushort_t* __restrict__ h_out)
{
    __shared__ short As[BM * LDSW];
    __shared__ short Ws[4 * BN * LDSW];
    __shared__ short DecIn[BM * DLW];

    const int tid  = threadIdx.x;
    const int wave = tid >> 6;
    const int lane = tid & 63;
    const int quad = lane >> 4;
    const int l15  = lane & 15;
    int row0, col0; tile_of(blockIdx.x, row0, col0);
    const int cg = col0 / BN;

    if (h1prev) {
        // fc: (64 rows of h1prev) @ fcw^T -> 64 x 128
        floatx4 a2[8];
#pragma unroll
        for (int n = 0; n < 8; ++n) a2[n] = (floatx4){0.f, 0.f, 0.f, 0.f};
        for (int kb = 0; kb < H_SZ; kb += KC) {
#pragma unroll
            for (int it = 0; it < 2; ++it) {
                int idx = tid + it * 256;
                int r = idx >> 3, cch = idx & 7;
                int4 v = *(const int4*)(const void*)(h1prev + (size_t)(row0 + r) * H_SZ + kb + cch * 8);
                *(int4*)(void*)&As[r * LDSW + cch * 8] = v;
            }
#pragma unroll
            for (int it = 0; it < 4; ++it) {
                int idx = tid + it * 256;          // 0..1023
                int r = idx >> 3, cch = idx & 7;   // r 0..127
                int4 v = *(const int4*)(const void*)(fcw + (size_t)r * H_SZ + kb + cch * 8);
                *(int4*)(void*)&Ws[r * LDSW + cch * 8] = v;
            }
            __syncthreads();
#pragma unroll
            for (int ks = 0; ks < 2; ++ks) {
                const int ko = ks * 32 + quad * 8;
                short8 a = *(const short8*)(const void*)&As[(wave * 16 + l15) * LDSW + ko];
#pragma unroll
                for (int n = 0; n < 8; ++n) {
                    short8 b = *(const short8*)(const void*)&Ws[(n * 16 + l15) * LDSW + ko];
                    a2[n] = __builtin_amdgcn_mfma_f32_16x16x32_bf16(a, b, a2[n], 0, 0, 0);
                }
            }
            __syncthreads();
        }
#pragma unroll
        for (int n = 0; n < 8; ++n) {
            const int col = n * 16 + l15;
            const float bias = fcb[col];
#pragma unroll
            for (int r = 0; r < 4; ++r) {
                const int lrow = wave * 16 + quad * 4 + r;
                const float v = a2[n][r] + bias;
                DecIn[lrow * DLW + col] = (short)f2bf(v);
                if (cg == 0 && outp)
                    outp[(size_t)(row0 + lrow) * T_DEC * I_SZ + col] = v;
            }
        }
    } else {
        // t==0: dec_in from global bf16 buffer
#pragma unroll
        for (int it = 0; it < 4; ++it) {
            int idx = tid + it * 256;              // 0..1023
            int r = idx >> 4, cch = idx & 15;
            int4 v = *(const int4*)(const void*)(dec0 + (size_t)(row0 + r) * I_SZ + cch * 8);
            *(int4*)(void*)&DecIn[r * DLW + cch * 8] = v;
        }
    }
    __syncthreads();

    // LSTM L0: K1=128 from DecIn (LDS), then h0 (global bf16)
    floatx4 acc[4][2];
#pragma unroll
    for (int g = 0; g < 4; ++g)
#pragma unroll
        for (int n = 0; n < 2; ++n)
            acc[g][n] = (floatx4){0.f, 0.f, 0.f, 0.f};

    const int KT = I_SZ + H_SZ;  // 640
    for (int kb = 0; kb < KT; kb += KC) {
        const ushort_t* wsrc; int wld;
        if (kb < I_SZ) { wsrc = W1 + kb;         wld = I_SZ;  }
        else           { wsrc = W2 + (kb - I_SZ); wld = H_SZ; }

        if (kb >= I_SZ) {
#pragma unroll
            for (int it = 0; it < 2; ++it) {
                int idx = tid + it * 256;
                int r = idx >> 3, cch = idx & 7;
                int4 v = *(const int4*)(const void*)(h0in + (size_t)(row0 + r) * H_SZ + (kb - I_SZ) + cch * 8);
                *(int4*)(void*)&As[r * LDSW + cch * 8] = v;
            }
        }
#pragma unroll
        for (int it = 0; it < 4; ++it) {
            int idx = tid + it * 256;
            int rr = idx >> 3, cch = idx & 7;
            int g = rr >> 5, r = rr & 31;
            int4 v = *(const int4*)(const void*)(wsrc + (size_t)(g * H_SZ + col0 + r) * wld + cch * 8);
            *(int4*)(void*)&Ws[rr * LDSW + cch * 8] = v;
        }
        __syncthreads();

#pragma unroll
        for (int ks = 0; ks < 2; ++ks) {
            const int ko = ks * 32 + quad * 8;
            short8 a;
            if (kb < I_SZ)
                a = *(const short8*)(const void*)&DecIn[(wave * 16 + l15) * DLW + kb + ko];
            else
                a = *(const short8*)(const void*)&As[(wave * 16 + l15) * LDSW + ko];
#pragma unroll
            for (int g = 0; g < 4; ++g)
#pragma unroll
                for (int n = 0; n < 2; ++n) {
                    short8 b = *(const short8*)(const void*)&Ws[(g * BN + n * 16 + l15) * LDSW + ko];
                    acc[g][n] = __builtin_amdgcn_mfma_f32_16x16x32_bf16(a, b, acc[g][n], 0, 0, 0);
                }
        }
        __syncthreads();
    }

#pragma unroll
    for (int n = 0; n < 2; ++n) {
        const int gcol = col0 + n * 16 + l15;
        const float bi = bih[0 * H_SZ + gcol] + bhh[0 * H_SZ + gcol];
        const float bf = bih[1 * H_SZ + gcol] + bhh[1 * H_SZ + gcol];
        const float bg = bih[2 * H_SZ + gcol] + bhh[2 * H_SZ + gcol];
        const float bo = bih[3 * H_SZ + gcol] + bhh[3 * H_SZ + gcol];
#pragma unroll
        for (int r = 0; r < 4; ++r) {
            const int grow = row0 + wave * 16 + quad * 4 + r;
            const size_t idx = (size_t)grow * H_SZ + gcol;
            const float zi = acc[0][n][r] + bi;
            const float zf = acc[1][n][r] + bf;
            const float zg = acc[2][n][r] + bg;
            const float zo = acc[3][n][r] + bo;
            const float cn = sigm(zf) * c[idx] + sigm(zi) * tanhf(zg);
            c[idx] = cn;
            h_out[idx] = f2bf(sigm(zo) * tanhf(cn));
        }
    }
}

// Final fc: out[:, T_DEC-1, :] = h1 @ fc_w^T + fc_b
__global__ __launch_bounds__(256) void fc_last(
    const ushort_t* __restrict__ h1, const ushort_t* __restrict__ fcw,
    const float* __restrict__ fcb, float* __restrict__ outp)
{
    __shared__ short As[64 * LDSW];
    __shared__ short Ws[64 * LDSW];
    const int tid  = threadIdx.x;
    const int wave = tid >> 6;
    const int lane = tid & 63;
    const int quad = lane >> 4;
    const int l15  = lane & 15;
    const int row0 = blockIdx.x * 64;
    const int col0 = blockIdx.y * 64;

    floatx4 acc[4];
#pragma unroll
    for (int n = 0; n < 4; ++n) acc[n] = (floatx4){0.f, 0.f, 0.f, 0.f};

    for (int kb = 0; kb < H_SZ; kb += KC) {
#pragma unroll
        for (int it = 0; it < 2; ++it) {
            int idx = tid + it * 256;
            int r = idx >> 3, cch = idx & 7;
            int4 va = *(const int4*)(const void*)(h1 + (size_t)(row0 + r) * H_SZ + kb + cch * 8);
            *(int4*)(void*)&As[r * LDSW + cch * 8] = va;
            int4 vw = *(const int4*)(const void*)(fcw + (size_t)(col0 + r) * H_SZ + kb + cch * 8);
            *(int4*)(void*)&Ws[r * LDSW + cch * 8] = vw;
        }
        __syncthreads();
#pragma unroll
        for (int ks = 0; ks < 2; ++ks) {
            const int ko = ks * 32 + quad * 8;
            short8 a = *(const short8*)(const void*)&As[(wave * 16 + l15) * LDSW + ko];
#pragma unroll
            for (int n = 0; n < 4; ++n) {
                short8 b = *(const short8*)(const void*)&Ws[(n * 16 + l15) * LDSW + ko];
                acc[n] = __builtin_amdgcn_mfma_f32_16x16x32_bf16(a, b, acc[n], 0, 0, 0);
            }
        }
        __syncthreads();
    }
#pragma unroll
    for (int n = 0; n < 4; ++n) {
        const int col = col0 + n * 16 + l15;
        const float bias = fcb[col];
#pragma unroll
        for (int r = 0; r < 4; ++r) {
            const int row = row0 + wave * 16 + quad * 4 + r;
            outp[(size_t)row * T_DEC * I_SZ + col] = acc[n][r] + bias;
        }
    }
}

extern "C" void kernel_launch(void* const* d_in, const int* in_sizes, int n_in,
                              void* d_out, int out_size, void* d_ws, size_t ws_size,
                              hipStream_t stream)
{
    const float* x     = (const float*)d_in[0];
    const float* W_ih0 = (const float*)d_in[1];
    const float* W_hh0 = (const float*)d_in[2];
    const float* b_ih0 = (const float*)d_in[3];
    const float* b_hh0 = (const float*)d_in[4];
    const float* W_ih1 = (const float*)d_in[5];
    const float* W_hh1 = (const float*)d_in[6];
    const float* b_ih1 = (const float*)d_in[7];
    const float* b_hh1 = (const float*)d_in[8];
    const float* fc_w  = (const float*)d_in[9];
    const float* fc_b  = (const float*)d_in[10];
    float* out = (float*)d_out;

    const int NW_IH0 = 4 * H_SZ * I_SZ;   // 262144
    const int NW_HH  = 4 * H_SZ * H_SZ;   // 1048576
    const int NW_FC  = I_SZ * H_SZ;       // 65536
    char* w = (char*)d_ws;
    ushort_t* wb_ih0 = (ushort_t*)w;  w += (size_t)NW_IH0 * 2;
    ushort_t* wb_hh0 = (ushort_t*)w;  w += (size_t)NW_HH  * 2;
    ushort_t* wb_ih1 = (ushort_t*)w;  w += (size_t)NW_HH  * 2;
    ushort_t* wb_hh1 = (ushort_t*)w;  w += (size_t)NW_HH  * 2;
    ushort_t* wb_fc  = (ushort_t*)w;  w += (size_t)NW_FC  * 2;
    const size_t HB2 = (size_t)B_SZ * H_SZ * 2;    // 1 MB bf16
    const size_t HB4 = (size_t)B_SZ * H_SZ * 4;    // 2 MB fp32
    ushort_t* h0a = (ushort_t*)w;  w += HB2;
    ushort_t* h0b = (ushort_t*)w;  w += HB2;
    ushort_t* h1a = (ushort_t*)w;  w += HB2;
    ushort_t* h1b = (ushort_t*)w;  w += HB2;
    float*    c0  = (float*)w;     w += HB4;
    float*    c1  = (float*)w;     w += HB4;
    ushort_t* dec0 = (ushort_t*)w; w += (size_t)B_SZ * I_SZ * 2;

    cvt_f32_bf16<<<NW_IH0 / 1024, 256, 0, stream>>>(W_ih0, wb_ih0, NW_IH0);
    cvt_f32_bf16<<<NW_HH  / 1024, 256, 0, stream>>>(W_hh0, wb_hh0, NW_HH);
    cvt_f32_bf16<<<NW_HH  / 1024, 256, 0, stream>>>(W_ih1, wb_ih1, NW_HH);
    cvt_f32_bf16<<<NW_HH  / 1024, 256, 0, stream>>>(W_hh1, wb_hh1, NW_HH);
    cvt_f32_bf16<<<NW_FC  / 1024, 256, 0, stream>>>(fc_w,  wb_fc,  NW_FC);

    hipMemsetAsync(h0a, 0, HB2, stream);
    hipMemsetAsync(h1a, 0, HB2, stream);
    hipMemsetAsync(c0, 0, HB4, stream);
    hipMemsetAsync(c1, 0, HB4, stream);
    copy_last<<<512, 256, 0, stream>>>(x, dec0);

    ushort_t *h0c = h0a, *h0n = h0b, *h1c = h1a, *h1n = h1b;

    // encoder, software-pipelined: launch t runs L0(t) and L1(t-1) concurrently
    for (int t = 0; t <= T_ENC; ++t) {
        const float* x_t = (t < T_ENC) ? x + (size_t)t * I_SZ : nullptr;
        const ushort_t* h0A = (t > 0) ? h0c : nullptr;   // h0(t-1) for L1
        enc_pair<<<512, 256, 0, stream>>>(x_t, T_ENC * I_SZ,
                                          wb_ih0, h0c, wb_hh0, b_ih0, b_hh0, c0, h0n,
                                          h0A,
                                          wb_ih1, h1c, wb_hh1, b_ih1, b_hh1, c1, h1n);
        if (t < T_ENC) { ushort_t* tmp = h0c; h0c = h0n; h0n = tmp; }
        if (t > 0)     { ushort_t* tmp = h1c; h1c = h1n; h1n = tmp; }
    }

    // decoder: [fc(t-1) + L0(t)] fused, then L1(t)
    for (int t = 0; t < T_DEC; ++t) {
        const ushort_t* h1prev = (t > 0) ? h1c : nullptr;
        float* outp = (t > 0) ? out + (size_t)(t - 1) * I_SZ : nullptr;
        dec_l0<<<256, 256, 0, stream>>>(h1prev, wb_fc, fc_b, outp, dec0,
                                        wb_ih0, h0c, wb_hh0, b_ih0, b_hh0, c0, h0n);
        { ushort_t* tmp = h0c; h0c = h0n; h0n = tmp; }
        lstm_one<<<256, 256, 0, stream>>>(h0c, H_SZ, H_SZ, wb_ih1, h1c, wb_hh1,
                                          b_ih1, b_hh1, c1, h1n);
        { ushort_t* tmp = h1c; h1c = h1n; h1n = tmp; }
    }
    fc_last<<<dim3(B_SZ / 64, I_SZ / 64), 256, 0, stream>>>(
        h1c, wb_fc, fc_b, out + (size_t)(T_DEC - 1) * I_SZ);
}